// Round 1
// baseline (119.439 us; speedup 1.0000x reference)
//
#include <hip/hip_runtime.h>

typedef __attribute__((ext_vector_type(8))) short bf16x8;
typedef __attribute__((ext_vector_type(4))) float f32x4;

static __device__ __forceinline__ short f2bf(float f) {
    union { float f; unsigned u; } v; v.f = f;
    unsigned r = v.u + 0x7fffu + ((v.u >> 16) & 1u);
    return (short)(r >> 16);
}

// ---- precompute 1: TLT bf16 [p=512][n0n1=64]  and  TR f32 [n23=64][m23=64][r24=8]
__global__ __launch_bounds__(256) void ht_pre1(const float* __restrict__ factors,
                                               const float* __restrict__ cores,
                                               short* __restrict__ TLT,
                                               float* __restrict__ TR) {
    int o = (blockIdx.x & 127) * 256 + threadIdx.x;
    if (blockIdx.x < 128) {
        // T_L[n0n1][p] = sum_{r01,r12} f0[n0][m0][r01] f1[n1][m1][r12] c1[r01][r12][r02]
        // stored transposed: TLT[p][n0n1], p = (m0*8+m1)*8 + r02
        int p = o >> 6, n01 = o & 63;
        int n0 = n01 >> 3, n1 = n01 & 7;
        int mm = p >> 3, r02 = p & 7;
        int m0 = mm >> 3, m1 = mm & 7;
        const float* f0 = factors + n0 * 64 + m0 * 8;
        const float* f1 = factors + 512 + n1 * 64 + m1 * 8;
        const float* c1 = cores + 512;
        float s = 0.f;
        #pragma unroll
        for (int r01 = 0; r01 < 8; ++r01) {
            float a = f0[r01];
            #pragma unroll
            for (int r12 = 0; r12 < 8; ++r12)
                s += a * f1[r12] * c1[r01 * 64 + r12 * 8 + r02];
        }
        TLT[p * 64 + n01] = f2bf(s);
    } else {
        // TR[n23][m23][r24] = sum_{r23,r34} f2[n2][m2][r23] f3[n3][m3][r34] c2[r23][r34][r24]
        int n23 = o >> 9, m23 = (o >> 3) & 63, r24 = o & 7;
        int n2 = n23 >> 3, n3 = n23 & 7, m2 = m23 >> 3, m3 = m23 & 7;
        const float* f2 = factors + 1024 + n2 * 64 + m2 * 8;
        const float* f3 = factors + 1536 + n3 * 64 + m3 * 8;
        const float* c2 = cores + 1024;
        float s = 0.f;
        #pragma unroll
        for (int r23 = 0; r23 < 8; ++r23) {
            float a = f2[r23];
            #pragma unroll
            for (int r34 = 0; r34 < 8; ++r34)
                s += a * f3[r34] * c2[r23 * 64 + r34 * 8 + r24];
        }
        TR[o] = s;
    }
}

// ---- precompute 2: VT bf16 [c=(m23*8+r)][k2=(r02*64+n23)]  (V transposed)
__global__ __launch_bounds__(256) void ht_pre2(const float* __restrict__ cores,
                                               const float* __restrict__ TR,
                                               short* __restrict__ VT) {
    int u = blockIdx.x * 256 + threadIdx.x;   // 65536 threads, 4 outputs each
    int base = u * 4;
    int c = base >> 9;
    int k2 = base & 511;
    int m23 = c >> 3, r = c & 7;
    int r02 = k2 >> 6;
    const float* c0 = cores;                  // c0[r02][r24][r]
    #pragma unroll
    for (int j = 0; j < 4; ++j) {
        int n23 = (k2 + j) & 63;
        float s = 0.f;
        #pragma unroll
        for (int r24 = 0; r24 < 8; ++r24)
            s += TR[n23 * 512 + m23 * 8 + r24] * c0[r02 * 64 + r24 * 8 + r];
        VT[base + j] = f2bf(s);
    }
}

// ---- main: per-b fused GEMM1 (Y = TLT^T . X_b) + GEMM2 (OUT = A . V)
__global__ __launch_bounds__(256, 2) void ht_main(const float* __restrict__ x,
                                                  const short* __restrict__ TLT,
                                                  const short* __restrict__ VT,
                                                  float* __restrict__ out) {
    __shared__ short XT[64 * 64];    // [n23][n01], XOR-swizzled, 16 KB
    __shared__ short YL[64 * 512];   // [m0m1][k2=(r02*64+n23)], XOR-swizzled, 64 KB

    const int t = threadIdx.x;
    const int b = blockIdx.x;
    const int w = t >> 6;
    const int l = t & 63;
    const int lr = l & 15;
    const int lk = l >> 4;

    // ---- phase 1: coalesced load x_b, convert bf16, transpose into XT
    {
        const float* xb = x + b * 4096;
        #pragma unroll
        for (int j = 0; j < 4; ++j) {
            f32x4 v = *(const f32x4*)(xb + j * 1024 + t * 4);
            int n01 = j * 16 + (t >> 4);
            int rbase = (t & 15) * 4;
            #pragma unroll
            for (int e = 0; e < 4; ++e) {
                int rr = rbase + e;   // n23 row
                XT[rr * 64 + (n01 ^ ((rr & 7) << 3))] = f2bf(v[e]);
            }
        }
    }
    __syncthreads();

    // ---- phase 2: GEMM1: Y[p=512][n23=64] = TLT[p][n01] * X[n01][n23]
    {
        bf16x8 bx[4][2];
        #pragma unroll
        for (int ct = 0; ct < 4; ++ct)
            #pragma unroll
            for (int kb = 0; kb < 2; ++kb) {
                int rr = ct * 16 + lr;          // n23 (B col)
                int cc = kb * 32 + lk * 8;      // n01 (k)
                bx[ct][kb] = *(const bf16x8*)&XT[rr * 64 + (cc ^ ((rr & 7) << 3))];
            }
        #pragma unroll
        for (int pt = 0; pt < 8; ++pt) {
            int pbase = w * 128 + pt * 16;
            const short* arow = TLT + (pbase + lr) * 64;
            bf16x8 a0 = *(const bf16x8*)&arow[lk * 8];
            bf16x8 a1 = *(const bf16x8*)&arow[32 + lk * 8];
            #pragma unroll
            for (int ct = 0; ct < 4; ++ct) {
                f32x4 acc = {0.f, 0.f, 0.f, 0.f};
                acc = __builtin_amdgcn_mfma_f32_16x16x32_bf16(a0, bx[ct][0], acc, 0, 0, 0);
                acc = __builtin_amdgcn_mfma_f32_16x16x32_bf16(a1, bx[ct][1], acc, 0, 0, 0);
                #pragma unroll
                for (int reg = 0; reg < 4; ++reg) {
                    int p = pbase + lk * 4 + reg;       // D row
                    int m = p >> 3;                      // m0m1
                    int c2 = (p & 7) * 64 + ct * 16 + lr; // k2 col
                    YL[m * 512 + (c2 ^ ((m & 7) << 3))] = f2bf(acc[reg]);
                }
            }
        }
    }
    __syncthreads();

    // ---- phase 3: GEMM2: OUT[m0m1=64][c=512] = A[m0m1][k2] * V[k2][c]
    {
        f32x4 acc[4][8];
        #pragma unroll
        for (int rt = 0; rt < 4; ++rt)
            #pragma unroll
            for (int ctl = 0; ctl < 8; ++ctl)
                acc[rt][ctl] = (f32x4){0.f, 0.f, 0.f, 0.f};

        for (int kb = 0; kb < 16; ++kb) {
            bf16x8 af[4];
            #pragma unroll
            for (int rt = 0; rt < 4; ++rt) {
                int m = rt * 16 + lr;
                int c2 = kb * 32 + lk * 8;
                af[rt] = *(const bf16x8*)&YL[m * 512 + (c2 ^ ((m & 7) << 3))];
            }
            bf16x8 bfr[8];
            #pragma unroll
            for (int ctl = 0; ctl < 8; ++ctl) {
                int c = (w * 8 + ctl) * 16 + lr;
                bfr[ctl] = *(const bf16x8*)&VT[c * 512 + kb * 32 + lk * 8];
            }
            #pragma unroll
            for (int rt = 0; rt < 4; ++rt)
                #pragma unroll
                for (int ctl = 0; ctl < 8; ++ctl)
                    acc[rt][ctl] = __builtin_amdgcn_mfma_f32_16x16x32_bf16(af[rt], bfr[ctl], acc[rt][ctl], 0, 0, 0);
        }

        float* ob = out + b * 32768;
        #pragma unroll
        for (int rt = 0; rt < 4; ++rt)
            #pragma unroll
            for (int ctl = 0; ctl < 8; ++ctl) {
                int col = (w * 8 + ctl) * 16 + lr;
                #pragma unroll
                for (int reg = 0; reg < 4; ++reg) {
                    int row = rt * 16 + lk * 4 + reg;
                    ob[row * 512 + col] = acc[rt][ctl][reg];
                }
            }
    }
}

extern "C" void kernel_launch(void* const* d_in, const int* in_sizes, int n_in,
                              void* d_out, int out_size, void* d_ws, size_t ws_size,
                              hipStream_t stream) {
    const float* x       = (const float*)d_in[0];   // (512,8,8,8,8)
    const float* factors = (const float*)d_in[1];   // (4,8,8,8)
    const float* cores   = (const float*)d_in[2];   // (3,8,8,8)
    float* out = (float*)d_out;                     // (512,8,8,8,8,8)

    short* TLT = (short*)d_ws;                              // 32768 bf16 = 64 KB
    short* VT  = TLT + 32768;                               // 262144 bf16 = 512 KB
    float* TR  = (float*)((char*)d_ws + 65536 + 524288);    // 32768 f32 = 128 KB

    hipLaunchKernelGGL(ht_pre1, dim3(256), dim3(256), 0, stream, factors, cores, TLT, TR);
    hipLaunchKernelGGL(ht_pre2, dim3(256), dim3(256), 0, stream, cores, TR, VT);
    hipLaunchKernelGGL(ht_main, dim3(512), dim3(256), 0, stream, x, TLT, VT, out);
}